// Round 8
// baseline (342.324 us; speedup 1.0000x reference)
//
#include <hip/hip_runtime.h>
#include <hip/hip_bf16.h>
#include <cstdint>
#include <cstddef>

constexpr int C_  = 256;
constexpr int H_  = 224;
constexpr int W_  = 224;
constexpr int P_  = 49;
constexpr int M_  = 1024;
constexpr int HW_ = H_ * W_;

constexpr size_t IMG_ELEMS = (size_t)4 * C_ * H_ * W_;
constexpr size_t SCO_ELEMS = (size_t)4 * M_ * P_ * P_;
constexpr size_t OFF_SC  = IMG_ELEMS;
constexpr size_t OFF_COV = OFF_SC  + SCO_ELEMS;
constexpr size_t OFF_L   = OFF_COV + SCO_ELEMS;
constexpr size_t OFF_EC  = OFF_L   + SCO_ELEMS;

typedef __attribute__((ext_vector_type(8))) short short8;
typedef __attribute__((ext_vector_type(4))) float f32x4;

// Workspace: patch-major bf16 staging, 56 p-slots per (bm,c) row (112B rows).
constexpr size_t WS_ROW   = 56;
constexpr size_t WS_PATCH = (size_t)C_ * WS_ROW;              // 14336 elems
constexpr size_t WS_HALF  = (size_t)4096 * WS_PATCH * 2;      // 117,440,512 B
constexpr size_t WS_NEED  = 2 * WS_HALF;                      // 234,881,024 B

// LDS byte map (compute kernel, 38,400 B -> 4 blocks/CU):
//   sA  : [0, 25088)        49 rows x 512B bf16, row-XOR-swizzled
//   Gb  : [25088, 31360)    49 rows x 128B bf16 (G - u); Lb overlays after cov
//   Scb : [31360, 37632)    49 rows x 128B bf16 Sc
//   u   : [37632, 37888)    64 f32
//   w   : [37888, 38144)    64 f32
//   T2  : [38144, 38400)    64 f32
// No fp32 G scratch: G lives in MFMA accumulators; softmax in-register
// (shfl over 16-lane q-groups); fp32 Sc carried in regs to the L epilogue
// (G-MFMA and cov-MFMA share the lane<->(p,q) map).
// Overflow-read audit (fragment rows 49..63): all overflow addresses stay
// inside the 38,400B block in finite-by-use-time regions, or feed only
// discarded D rows/cols (G/cov) / Lb's zero k-columns (Ec).
constexpr int SA_OFF  = 0;
constexpr int GB_OFF  = 25088;
constexpr int SCB_OFF = 31360;
constexpr int U_OFF   = 37632;
constexpr int W_OFF   = 37888;
constexpr int T2_OFF  = 38144;
constexpr int SMEM_BYTES = 38400;

__device__ __forceinline__ int srowswz(int r) { return ((r ^ (r >> 3)) & 7) << 4; }

template<bool SPLIT>
__global__ __launch_bounds__(256, 4)
void psa_kernel(const float* __restrict__ x, const float* __restrict__ betap,
                float* __restrict__ out_img, float* __restrict__ out_sc,
                float* __restrict__ out_cov, float* __restrict__ out_l,
                float* __restrict__ out_ec,
                __hip_bfloat16* __restrict__ ws_ec,
                __hip_bfloat16* __restrict__ ws_out)
{
    __shared__ __align__(16) unsigned char smem[SMEM_BYTES];
    float* uArr  = (float*)(smem + U_OFF);
    float* wArr  = (float*)(smem + W_OFF);
    float* t2Arr = (float*)(smem + T2_OFF);

    const int tid = threadIdx.x;
    const int bid = blockIdx.x;
    const int bm  = ((bid & 7) << 9) | (bid >> 3);   // XCD-bijective swizzle
    const int b   = bm >> 10;
    const int m   = bm & (M_ - 1);
    const int mh  = m >> 5;
    const int mw  = m & 31;
    const float beta = betap[0];
    const size_t xpatch = (((size_t)b * C_ * H_) + (size_t)mh * 7) * W_ + (size_t)mw * 7;

    const int wid = tid >> 6, lane = tid & 63, l15 = lane & 15, lh = lane >> 4;

    // ---- Phase 0: stage x -> sA (bf16, swizzled). thread = channel ----
    {
        const int c = tid;
        const float* src = x + xpatch + (size_t)c * HW_;
        #pragma unroll
        for (int i = 0; i < 7; ++i) {
            #pragma unroll
            for (int j = 0; j < 7; ++j) {
                const int p = i * 7 + j;
                *(__hip_bfloat16*)(smem + SA_OFF + p * 512 + ((2 * c) ^ srowswz(p))) =
                    __float2bfloat16(src[i * W_ + j]);
            }
        }
    }
    __syncthreads();

    // ---- Phase 1: G = A A^T (MFMA, K=256); G stays in registers ----
    f32x4 gacc[4] = {f32x4{0,0,0,0}, f32x4{0,0,0,0}, f32x4{0,0,0,0}, f32x4{0,0,0,0}};
    {
        const int arow = 16 * wid + l15;
        #pragma unroll
        for (int kc = 0; kc < 8; ++kc) {
            const int cb = 64 * kc + 16 * lh;
            const short8 af = *(const short8*)(smem + SA_OFF + arow * 512 + (cb ^ srowswz(arow)));
            #pragma unroll
            for (int t = 0; t < 4; ++t) {
                const int brow = 16 * t + l15;
                const short8 bf = *(const short8*)(smem + SA_OFF + brow * 512 + (cb ^ srowswz(brow)));
                gacc[t] = __builtin_amdgcn_mfma_f32_16x16x32_bf16(af, bf, gacc[t], 0, 0, 0);
            }
        }
    }

    // ---- Phase 2: in-register row stats. Lane holds G[p][q], p=16wid+4lh+r,
    // q=16t+l15. Reduce over q: in-reg t-fold + shfl within 16-lane groups. ----
    float mx[4];
    {
        #pragma unroll
        for (int r = 0; r < 4; ++r) {
            const int p = 16 * wid + 4 * lh + r;
            float m_ = fmaxf(fmaxf(gacc[0][r], gacc[1][r]), gacc[2][r]);
            m_ = fmaxf(m_, (l15 == 0) ? gacc[3][r] : -3.4e38f);
            float s_ = gacc[0][r] + gacc[1][r] + gacc[2][r] + ((l15 == 0) ? gacc[3][r] : 0.f);
            #pragma unroll
            for (int d = 1; d < 16; d <<= 1) {
                m_ = fmaxf(m_, __shfl_xor(m_, d));
                s_ += __shfl_xor(s_, d);
            }
            mx[r] = m_;
            if (l15 == 0 && p <= 48) uArr[p] = s_ * (1.f / 49.f);   // u = rowmean (G sym)
        }
    }
    __syncthreads();

    // ---- Phase 3: Gb = bf16(G-u); in-reg exp/rowsum/scale; Scb + Sc global ----
    float sc[4][4];   // fp32 Sc carried to the L epilogue
    {
        float* sc_g = out_sc + (size_t)bm * (P_ * P_);
        #pragma unroll
        for (int r = 0; r < 4; ++r) {
            const int p = 16 * wid + 4 * lh + r;
            if (p <= 48) {
                #pragma unroll
                for (int t = 0; t < 4; ++t) {
                    const int qv = 16 * t + l15;
                    const float gv = (qv <= 48) ? (gacc[t][r] - uArr[qv]) : 0.f;
                    *(__hip_bfloat16*)(smem + GB_OFF + p * 128 + ((2 * qv) ^ srowswz(p))) =
                        __float2bfloat16(gv);
                }
            }
            float e[4];
            #pragma unroll
            for (int t = 0; t < 4; ++t) {
                const int qv = 16 * t + l15;
                e[t] = (qv <= 48) ? __expf(gacc[t][r] - mx[r]) : 0.f;
            }
            float s_ = e[0] + e[1] + e[2] + e[3];
            #pragma unroll
            for (int d = 1; d < 16; d <<= 1) s_ += __shfl_xor(s_, d);
            const float rinv = 1.f / s_;
            #pragma unroll
            for (int t = 0; t < 4; ++t) sc[t][r] = e[t] * rinv;
            if (p <= 48) {
                #pragma unroll
                for (int t = 0; t < 4; ++t) {
                    const int qv = 16 * t + l15;
                    *(__hip_bfloat16*)(smem + SCB_OFF + p * 128 + ((2 * qv) ^ srowswz(p))) =
                        __float2bfloat16(sc[t][r]);        // qv>48 stores 0
                    if (qv <= 48) sc_g[p * 49 + qv] = sc[t][r];
                }
            }
        }
    }
    __syncthreads();

    // ---- Phase 4: w = colmean(Sc) from Scb. 196 threads ----
    if (tid < 196) {
        const int r0 = tid >> 2, s = tid & 3;
        const int pa = s * 13, pb = (pa + 13 < 49) ? pa + 13 : 49;
        float sm = 0.f;
        for (int p = pa; p < pb; ++p)
            sm += __bfloat162float(
                *(const __hip_bfloat16*)(smem + SCB_OFF + p * 128 + ((2 * r0) ^ srowswz(p))));
        sm += __shfl_xor(sm, 1);
        sm += __shfl_xor(sm, 2);
        if (s == 0) wArr[r0] = sm * (1.f / 49.f);
    }
    __syncthreads();

    // ---- Phase 5: T2[p] = sum_r Gb[p][r] * w[r] ----
    if (tid < 196) {
        const int p0 = tid >> 2, s = tid & 3;
        const int ra = s * 13, rb = (ra + 13 < 49) ? ra + 13 : 49;
        float sm = 0.f;
        for (int r = ra; r < rb; ++r) {
            const float gb = __bfloat162float(
                *(const __hip_bfloat16*)(smem + GB_OFF + p0 * 128 + ((2 * r) ^ srowswz(p0))));
            sm += gb * wArr[r];
        }
        sm += __shfl_xor(sm, 1);
        sm += __shfl_xor(sm, 2);
        if (s == 0) t2Arr[p0] = sm;
    }
    __syncthreads();

    // ---- Phase 6: cov MFMA: D = Gb . Scb^T (K=64) ----
    f32x4 cacc[4] = {f32x4{0,0,0,0}, f32x4{0,0,0,0}, f32x4{0,0,0,0}, f32x4{0,0,0,0}};
    {
        const int arow = 16 * wid + l15;
        #pragma unroll
        for (int kc = 0; kc < 2; ++kc) {
            const int cb = 64 * kc + 16 * lh;
            const short8 af = *(const short8*)(smem + GB_OFF + arow * 128 + (cb ^ srowswz(arow)));
            #pragma unroll
            for (int t = 0; t < 4; ++t) {
                const int brow = 16 * t + l15;
                const short8 bf = *(const short8*)(smem + SCB_OFF + brow * 128 + (cb ^ srowswz(brow)));
                cacc[t] = __builtin_amdgcn_mfma_f32_16x16x32_bf16(af, bf, cacc[t], 0, 0, 0);
            }
        }
    }
    __syncthreads();   // cov reads done before Lb overlays Gb

    // ---- Phase 7: cv = (cacc - T2[p])/49; L = Sc + cv; write cov/L/Lb ----
    {
        float* cov_g = out_cov + (size_t)bm * (P_ * P_);
        float* l_g   = out_l   + (size_t)bm * (P_ * P_);
        #pragma unroll
        for (int t = 0; t < 4; ++t) {
            const int qv = 16 * t + l15;
            #pragma unroll
            for (int r = 0; r < 4; ++r) {
                const int p = 16 * wid + 4 * lh + r;
                if (p <= 48 && qv <= 48) {
                    const float cv = (cacc[t][r] - t2Arr[p]) * (1.f / 49.f);
                    const float lv = sc[t][r] + cv;
                    cov_g[p * 49 + qv] = cv;
                    l_g  [p * 49 + qv] = lv;
                    *(__hip_bfloat16*)(smem + GB_OFF + p * 128 + ((2 * qv) ^ srowswz(p))) =
                        __float2bfloat16(lv);   // Lb; cols 49..63 keep zeros
                }
            }
        }
    }
    __syncthreads();

    // ---- Phase 8: Ec^T = A^T . L^T (D[c][p]); wave wid -> c in [64wid, +64) ----
    {
        f32x4 acc[4][4];   // [ct][pt]
        #pragma unroll
        for (int i = 0; i < 4; ++i)
            #pragma unroll
            for (int j2 = 0; j2 < 4; ++j2) acc[i][j2] = f32x4{0, 0, 0, 0};

        #pragma unroll
        for (int kc = 0; kc < 2; ++kc) {
            const int cb = 64 * kc + 16 * lh;
            short8 bf[4];
            #pragma unroll
            for (int pt = 0; pt < 4; ++pt) {
                const int brow = 16 * pt + l15;
                bf[pt] = *(const short8*)(smem + GB_OFF + brow * 128 + (cb ^ srowswz(brow)));
            }
            #pragma unroll
            for (int ct = 0; ct < 4; ++ct) {
                const int c = 64 * wid + 16 * ct + l15;
                short8 af;
                #pragma unroll
                for (int j = 0; j < 8; ++j) {
                    const int q2 = 32 * kc + 8 * lh + j;
                    af[j] = *(const short*)(smem + SA_OFF + q2 * 512 + ((2 * c) ^ srowswz(q2)));
                }
                #pragma unroll
                for (int pt = 0; pt < 4; ++pt)
                    acc[ct][pt] = __builtin_amdgcn_mfma_f32_16x16x32_bf16(af, bf[pt], acc[ct][pt], 0, 0, 0);
            }
        }

        if (SPLIT) {
            // Patch-major bf16 staging (56-slot rows): 32B/16B store segments,
            // full patch region written contiguously by this block.
            __hip_bfloat16* wec = ws_ec  + (size_t)bm * WS_PATCH;
            __hip_bfloat16* wou = ws_out + (size_t)bm * WS_PATCH;
            #pragma unroll
            for (int pt = 0; pt < 4; ++pt) {
                const int p = 16 * pt + l15;
                if (p >= (int)WS_ROW) continue;   // pt==3: only l15<8
                #pragma unroll
                for (int ct = 0; ct < 4; ++ct) {
                    #pragma unroll
                    for (int r = 0; r < 4; ++r) {
                        const int c = 64 * wid + 16 * ct + 4 * lh + r;
                        const float ec = acc[ct][pt][r];
                        const float xv = __bfloat162float(
                            *(const __hip_bfloat16*)(smem + SA_OFF + p * 512 + ((2 * c) ^ srowswz(p))));
                        wec[(size_t)c * WS_ROW + p] = __float2bfloat16(ec);
                        wou[(size_t)c * WS_ROW + p] = __float2bfloat16(xv * fmaf(beta, ec, xv));
                    }
                }
            }
        } else {
            #pragma unroll
            for (int pt = 0; pt < 4; ++pt) {
                const int p = 16 * pt + l15;
                if (p > 48) continue;
                const int i = p / 7, j = p - 7 * (p / 7);
                const size_t base = xpatch + (size_t)i * W_ + j;
                #pragma unroll
                for (int ct = 0; ct < 4; ++ct) {
                    #pragma unroll
                    for (int r = 0; r < 4; ++r) {
                        const int c = 64 * wid + 16 * ct + 4 * lh + r;
                        const size_t g = base + (size_t)c * HW_;
                        const float ec = acc[ct][pt][r];
                        const float xv = __bfloat162float(
                            *(const __hip_bfloat16*)(smem + SA_OFF + p * 512 + ((2 * c) ^ srowswz(p))));
                        out_ec [g] = ec;
                        out_img[g] = xv * fmaf(beta, ec, xv);
                    }
                }
            }
        }
    }
}

// Fold: one block per (b,c,mh) strip. Stage 32 patches' (c,:) rows from ws
// into LDS, emit out_img/out_ec as full-line coalesced float4 stores.
__global__ __launch_bounds__(256)
void fold_kernel(const __hip_bfloat16* __restrict__ ws_ec,
                 const __hip_bfloat16* __restrict__ ws_out,
                 float* __restrict__ out_img, float* __restrict__ out_ec)
{
    __shared__ __hip_bfloat16 lec[32][56];
    __shared__ __hip_bfloat16 lou[32][56];

    const int bid = blockIdx.x;
    const int bc  = bid >> 5;         // b*256 + c
    const int mh  = bid & 31;
    const int b   = bc >> 8;
    const int c   = bc & 255;
    const int t   = threadIdx.x;

    // Stage: 32 rows x 7 short8 (56 slots; 49..55 garbage, ignored below).
    if (t < 224) {
        const int k = t / 7, o = (t - k * 7) * 8;
        const size_t base = (((size_t)(b << 10) + (mh << 5) + k) * C_ + c) * WS_ROW + o;
        *(short8*)&lec[k][o] = *(const short8*)&ws_ec [base];
        *(short8*)&lou[k][o] = *(const short8*)&ws_out[base];
    }
    __syncthreads();

    const size_t rowbase = ((size_t)bc * H_ + (size_t)mh * 7) * W_;
    for (int idx = t; idx < 392; idx += 256) {
        const int i  = idx / 56;
        const int w0 = (idx - i * 56) * 4;
        float4 vo, ve;
        #pragma unroll
        for (int e = 0; e < 4; ++e) {
            const int w  = w0 + e;
            const int mw = w / 7;
            const int p  = i * 7 + (w - mw * 7);
            ((float*)&ve)[e] = __bfloat162float(lec[mw][p]);
            ((float*)&vo)[e] = __bfloat162float(lou[mw][p]);
        }
        *(float4*)&out_ec [rowbase + (size_t)i * W_ + w0] = ve;
        *(float4*)&out_img[rowbase + (size_t)i * W_ + w0] = vo;
    }
}

extern "C" void kernel_launch(void* const* d_in, const int* in_sizes, int n_in,
                              void* d_out, int out_size, void* d_ws, size_t ws_size,
                              hipStream_t stream) {
    const float* x    = (const float*)d_in[0];
    const float* beta = (const float*)d_in[1];
    float* out = (float*)d_out;

    if (ws_size >= WS_NEED) {
        __hip_bfloat16* ws_ec  = (__hip_bfloat16*)d_ws;
        __hip_bfloat16* ws_out = (__hip_bfloat16*)((unsigned char*)d_ws + WS_HALF);
        psa_kernel<true><<<dim3(4 * M_), dim3(256), 0, stream>>>(
            x, beta, out, out + OFF_SC, out + OFF_COV, out + OFF_L, out + OFF_EC,
            ws_ec, ws_out);
        fold_kernel<<<dim3(1024 * 32), dim3(256), 0, stream>>>(
            ws_ec, ws_out, out, out + OFF_EC);
    } else {
        psa_kernel<false><<<dim3(4 * M_), dim3(256), 0, stream>>>(
            x, beta, out, out + OFF_SC, out + OFF_COV, out + OFF_L, out + OFF_EC,
            nullptr, nullptr);
    }
}

// Round 9
// 283.200 us; speedup vs baseline: 1.2088x; 1.2088x over previous
//
#include <hip/hip_runtime.h>
#include <hip/hip_bf16.h>
#include <cstdint>
#include <cstddef>

constexpr int C_  = 256;
constexpr int H_  = 224;
constexpr int W_  = 224;
constexpr int P_  = 49;
constexpr int M_  = 1024;
constexpr int HW_ = H_ * W_;

constexpr size_t IMG_ELEMS = (size_t)4 * C_ * H_ * W_;
constexpr size_t SCO_ELEMS = (size_t)4 * M_ * P_ * P_;
constexpr size_t OFF_SC  = IMG_ELEMS;
constexpr size_t OFF_COV = OFF_SC  + SCO_ELEMS;
constexpr size_t OFF_L   = OFF_COV + SCO_ELEMS;
constexpr size_t OFF_EC  = OFF_L   + SCO_ELEMS;

typedef __attribute__((ext_vector_type(8))) short short8;
typedef __attribute__((ext_vector_type(4))) float f32x4;

// Workspace: patch-major bf16 Ec staging, 56 p-slots per (bm,c) row (112B).
constexpr size_t WS_ROW   = 56;
constexpr size_t WS_PATCH = (size_t)C_ * WS_ROW;              // 14336 elems
constexpr size_t WS_NEED  = (size_t)4096 * WS_PATCH * 2;      // 117,440,512 B

// LDS byte map (compute kernel, 37,888 B -> 4 blocks/CU):
//   sA  : [0, 25088)        49 rows x 512B bf16, row-XOR-swizzled
//   Gb  : [25088, 31360)    49 rows x 128B bf16 (G - u); Lb overlays after cov
//   Scb : [31360, 37632)    49 rows x 128B bf16 Sc
//   u   : [37632, 37888)    64 f32
// G lives in MFMA accumulators; softmax in-register (shfl over 16-lane
// q-groups); fp32 Sc carried in regs to the L epilogue; T2 computed
// in-register as rowmean of the cov-MFMA accumulator (exact identity:
// T2[p] = sum_r Gb[p][r] w[r] = (1/49) sum_{q<=48} (Gb.Scb^T)[p][q]).
// Overflow-read audit (fragment rows 49..63): overflow regions are finite
// bf16/f32-reinterp by use time or (beyond the block) benign OOB; all such
// products land only in discarded/masked D rows/cols or multiply Lb's zero
// k-columns. Same audit as R5-R8 (passed repeatedly).
constexpr int SA_OFF  = 0;
constexpr int GB_OFF  = 25088;
constexpr int SCB_OFF = 31360;
constexpr int U_OFF   = 37632;
constexpr int SMEM_BYTES = 37888;

__device__ __forceinline__ int srowswz(int r) { return ((r ^ (r >> 3)) & 7) << 4; }

template<bool SPLIT>
__global__ __launch_bounds__(256, 4)
void psa_kernel(const float* __restrict__ x, const float* __restrict__ betap,
                float* __restrict__ out_img, float* __restrict__ out_sc,
                float* __restrict__ out_cov, float* __restrict__ out_l,
                float* __restrict__ out_ec,
                __hip_bfloat16* __restrict__ ws_ec)
{
    __shared__ __align__(16) unsigned char smem[SMEM_BYTES];
    float* uArr = (float*)(smem + U_OFF);

    const int tid = threadIdx.x;
    const int bid = blockIdx.x;
    const int bm  = ((bid & 7) << 9) | (bid >> 3);   // XCD-bijective swizzle
    const int b   = bm >> 10;
    const int m   = bm & (M_ - 1);
    const int mh  = m >> 5;
    const int mw  = m & 31;
    const float beta = betap[0];
    const size_t xpatch = (((size_t)b * C_ * H_) + (size_t)mh * 7) * W_ + (size_t)mw * 7;

    const int wid = tid >> 6, lane = tid & 63, l15 = lane & 15, lh = lane >> 4;

    // ---- Phase 0: stage x -> sA (bf16, swizzled). thread = channel ----
    {
        const int c = tid;
        const float* src = x + xpatch + (size_t)c * HW_;
        #pragma unroll
        for (int i = 0; i < 7; ++i) {
            #pragma unroll
            for (int j = 0; j < 7; ++j) {
                const int p = i * 7 + j;
                *(__hip_bfloat16*)(smem + SA_OFF + p * 512 + ((2 * c) ^ srowswz(p))) =
                    __float2bfloat16(src[i * W_ + j]);
            }
        }
    }
    __syncthreads();

    // ---- Phase 1: G = A A^T (MFMA, K=256); G stays in registers ----
    f32x4 gacc[4] = {f32x4{0,0,0,0}, f32x4{0,0,0,0}, f32x4{0,0,0,0}, f32x4{0,0,0,0}};
    {
        const int arow = 16 * wid + l15;
        #pragma unroll
        for (int kc = 0; kc < 8; ++kc) {
            const int cb = 64 * kc + 16 * lh;
            const short8 af = *(const short8*)(smem + SA_OFF + arow * 512 + (cb ^ srowswz(arow)));
            #pragma unroll
            for (int t = 0; t < 4; ++t) {
                const int brow = 16 * t + l15;
                const short8 bf = *(const short8*)(smem + SA_OFF + brow * 512 + (cb ^ srowswz(brow)));
                gacc[t] = __builtin_amdgcn_mfma_f32_16x16x32_bf16(af, bf, gacc[t], 0, 0, 0);
            }
        }
    }

    // ---- Phase 2: in-register row stats (lane holds G[p][q], p=16wid+4lh+r,
    // q=16t+l15); u = rowmean (G symmetric) ----
    float mx[4];
    {
        #pragma unroll
        for (int r = 0; r < 4; ++r) {
            const int p = 16 * wid + 4 * lh + r;
            float m_ = fmaxf(fmaxf(gacc[0][r], gacc[1][r]), gacc[2][r]);
            m_ = fmaxf(m_, (l15 == 0) ? gacc[3][r] : -3.4e38f);
            float s_ = gacc[0][r] + gacc[1][r] + gacc[2][r] + ((l15 == 0) ? gacc[3][r] : 0.f);
            #pragma unroll
            for (int d = 1; d < 16; d <<= 1) {
                m_ = fmaxf(m_, __shfl_xor(m_, d));
                s_ += __shfl_xor(s_, d);
            }
            mx[r] = m_;
            if (l15 == 0 && p <= 48) uArr[p] = s_ * (1.f / 49.f);
        }
    }
    __syncthreads();

    // ---- Phase 3: Gb = bf16(G-u); in-reg exp/rowsum/scale; Scb + Sc global ----
    float sc[4][4];   // fp32 Sc carried to the L epilogue
    {
        float* sc_g = out_sc + (size_t)bm * (P_ * P_);
        #pragma unroll
        for (int r = 0; r < 4; ++r) {
            const int p = 16 * wid + 4 * lh + r;
            if (p <= 48) {
                #pragma unroll
                for (int t = 0; t < 4; ++t) {
                    const int qv = 16 * t + l15;
                    const float gv = (qv <= 48) ? (gacc[t][r] - uArr[qv]) : 0.f;
                    *(__hip_bfloat16*)(smem + GB_OFF + p * 128 + ((2 * qv) ^ srowswz(p))) =
                        __float2bfloat16(gv);
                }
            }
            float e[4];
            #pragma unroll
            for (int t = 0; t < 4; ++t) {
                const int qv = 16 * t + l15;
                e[t] = (qv <= 48) ? __expf(gacc[t][r] - mx[r]) : 0.f;
            }
            float s_ = e[0] + e[1] + e[2] + e[3];
            #pragma unroll
            for (int d = 1; d < 16; d <<= 1) s_ += __shfl_xor(s_, d);
            const float rinv = 1.f / s_;
            #pragma unroll
            for (int t = 0; t < 4; ++t) sc[t][r] = e[t] * rinv;
            if (p <= 48) {
                #pragma unroll
                for (int t = 0; t < 4; ++t) {
                    const int qv = 16 * t + l15;
                    *(__hip_bfloat16*)(smem + SCB_OFF + p * 128 + ((2 * qv) ^ srowswz(p))) =
                        __float2bfloat16(sc[t][r]);        // qv>48 stores 0
                    if (qv <= 48) sc_g[p * 49 + qv] = sc[t][r];
                }
            }
        }
    }
    __syncthreads();

    // ---- Phase 4: cov MFMA: cacc = Gb . Scb^T (K=64); T2 = rowmean in-reg ----
    f32x4 cacc[4] = {f32x4{0,0,0,0}, f32x4{0,0,0,0}, f32x4{0,0,0,0}, f32x4{0,0,0,0}};
    {
        const int arow = 16 * wid + l15;
        #pragma unroll
        for (int kc = 0; kc < 2; ++kc) {
            const int cb = 64 * kc + 16 * lh;
            const short8 af = *(const short8*)(smem + GB_OFF + arow * 128 + (cb ^ srowswz(arow)));
            #pragma unroll
            for (int t = 0; t < 4; ++t) {
                const int brow = 16 * t + l15;
                const short8 bf = *(const short8*)(smem + SCB_OFF + brow * 128 + (cb ^ srowswz(brow)));
                cacc[t] = __builtin_amdgcn_mfma_f32_16x16x32_bf16(af, bf, cacc[t], 0, 0, 0);
            }
        }
    }
    float t2[4];
    {
        #pragma unroll
        for (int r = 0; r < 4; ++r) {
            float s_ = cacc[0][r] + cacc[1][r] + cacc[2][r] + ((l15 == 0) ? cacc[3][r] : 0.f);
            #pragma unroll
            for (int d = 1; d < 16; d <<= 1) s_ += __shfl_xor(s_, d);
            t2[r] = s_ * (1.f / 49.f);
        }
    }
    __syncthreads();   // cov reads done before Lb overlays Gb

    // ---- Phase 5: cv = (cacc - T2)/49; L = Sc + cv; write cov/L/Lb ----
    {
        float* cov_g = out_cov + (size_t)bm * (P_ * P_);
        float* l_g   = out_l   + (size_t)bm * (P_ * P_);
        #pragma unroll
        for (int t = 0; t < 4; ++t) {
            const int qv = 16 * t + l15;
            #pragma unroll
            for (int r = 0; r < 4; ++r) {
                const int p = 16 * wid + 4 * lh + r;
                if (p <= 48 && qv <= 48) {
                    const float cv = (cacc[t][r] - t2[r]) * (1.f / 49.f);
                    const float lv = sc[t][r] + cv;
                    cov_g[p * 49 + qv] = cv;
                    l_g  [p * 49 + qv] = lv;
                    *(__hip_bfloat16*)(smem + GB_OFF + p * 128 + ((2 * qv) ^ srowswz(p))) =
                        __float2bfloat16(lv);   // Lb; cols 49..63 keep zeros
                }
            }
        }
    }
    __syncthreads();

    // ---- Phase 6: Ec^T = A^T . L^T (D[c][p]); wave wid -> c in [64wid, +64) ----
    {
        f32x4 acc[4][4];   // [ct][pt]
        #pragma unroll
        for (int i = 0; i < 4; ++i)
            #pragma unroll
            for (int j2 = 0; j2 < 4; ++j2) acc[i][j2] = f32x4{0, 0, 0, 0};

        #pragma unroll
        for (int kc = 0; kc < 2; ++kc) {
            const int cb = 64 * kc + 16 * lh;
            short8 bf[4];
            #pragma unroll
            for (int pt = 0; pt < 4; ++pt) {
                const int brow = 16 * pt + l15;
                bf[pt] = *(const short8*)(smem + GB_OFF + brow * 128 + (cb ^ srowswz(brow)));
            }
            #pragma unroll
            for (int ct = 0; ct < 4; ++ct) {
                const int c = 64 * wid + 16 * ct + l15;
                short8 af;
                #pragma unroll
                for (int j = 0; j < 8; ++j) {
                    const int q2 = 32 * kc + 8 * lh + j;
                    af[j] = *(const short*)(smem + SA_OFF + q2 * 512 + ((2 * c) ^ srowswz(q2)));
                }
                #pragma unroll
                for (int pt = 0; pt < 4; ++pt)
                    acc[ct][pt] = __builtin_amdgcn_mfma_f32_16x16x32_bf16(af, bf[pt], acc[ct][pt], 0, 0, 0);
            }
        }

        if (SPLIT) {
            // Patch-major bf16 Ec staging (56-slot rows).
            __hip_bfloat16* wec = ws_ec + (size_t)bm * WS_PATCH;
            #pragma unroll
            for (int pt = 0; pt < 4; ++pt) {
                const int p = 16 * pt + l15;
                if (p >= (int)WS_ROW) continue;   // pt==3: only l15<8
                #pragma unroll
                for (int ct = 0; ct < 4; ++ct) {
                    #pragma unroll
                    for (int r = 0; r < 4; ++r) {
                        const int c = 64 * wid + 16 * ct + 4 * lh + r;
                        wec[(size_t)c * WS_ROW + p] = __float2bfloat16(acc[ct][pt][r]);
                    }
                }
            }
        } else {
            #pragma unroll
            for (int pt = 0; pt < 4; ++pt) {
                const int p = 16 * pt + l15;
                if (p > 48) continue;
                const int i = p / 7, j = p - 7 * (p / 7);
                const size_t base = xpatch + (size_t)i * W_ + j;
                #pragma unroll
                for (int ct = 0; ct < 4; ++ct) {
                    #pragma unroll
                    for (int r = 0; r < 4; ++r) {
                        const int c = 64 * wid + 16 * ct + 4 * lh + r;
                        const size_t g = base + (size_t)c * HW_;
                        const float ec = acc[ct][pt][r];
                        const float xv = __bfloat162float(
                            *(const __hip_bfloat16*)(smem + SA_OFF + p * 512 + ((2 * c) ^ srowswz(p))));
                        out_ec [g] = ec;
                        out_img[g] = xv * fmaf(beta, ec, xv);
                    }
                }
            }
        }
    }
}

// Fold: one block per (b,c,mh) strip. Stage 32 patches' (c,:) Ec rows from
// ws into LDS; read x coalesced (fp32); emit out_img/out_ec as full-line
// coalesced float4 stores.
__global__ __launch_bounds__(256)
void fold_kernel(const __hip_bfloat16* __restrict__ ws_ec,
                 const float* __restrict__ x, const float* __restrict__ betap,
                 float* __restrict__ out_img, float* __restrict__ out_ec)
{
    __shared__ __hip_bfloat16 lec[32][56];

    const int bid = blockIdx.x;
    const int bc  = bid >> 5;         // b*256 + c
    const int mh  = bid & 31;
    const int b   = bc >> 8;
    const int c   = bc & 255;
    const int t   = threadIdx.x;
    const float beta = betap[0];

    // Stage: 32 rows x 7 short8 (56 slots; 49..55 garbage, ignored below).
    if (t < 224) {
        const int k = t / 7, o = (t - k * 7) * 8;
        const size_t base = (((size_t)(b << 10) + (mh << 5) + k) * C_ + c) * WS_ROW + o;
        *(short8*)&lec[k][o] = *(const short8*)&ws_ec[base];
    }
    __syncthreads();

    const size_t rowbase = ((size_t)bc * H_ + (size_t)mh * 7) * W_;
    for (int idx = t; idx < 392; idx += 256) {
        const int i  = idx / 56;
        const int w0 = (idx - i * 56) * 4;
        const size_t g = rowbase + (size_t)i * W_ + w0;
        const float4 xv = *(const float4*)&x[g];
        float4 vo, ve;
        #pragma unroll
        for (int e = 0; e < 4; ++e) {
            const int w  = w0 + e;
            const int mw = w / 7;
            const int p  = i * 7 + (w - mw * 7);
            const float ec = __bfloat162float(lec[mw][p]);
            const float xe = ((const float*)&xv)[e];
            ((float*)&ve)[e] = ec;
            ((float*)&vo)[e] = xe * fmaf(beta, ec, xe);
        }
        *(float4*)&out_ec [g] = ve;
        *(float4*)&out_img[g] = vo;
    }
}

extern "C" void kernel_launch(void* const* d_in, const int* in_sizes, int n_in,
                              void* d_out, int out_size, void* d_ws, size_t ws_size,
                              hipStream_t stream) {
    const float* x    = (const float*)d_in[0];
    const float* beta = (const float*)d_in[1];
    float* out = (float*)d_out;

    if (ws_size >= WS_NEED) {
        __hip_bfloat16* ws_ec = (__hip_bfloat16*)d_ws;
        psa_kernel<true><<<dim3(4 * M_), dim3(256), 0, stream>>>(
            x, beta, out, out + OFF_SC, out + OFF_COV, out + OFF_L, out + OFF_EC,
            ws_ec);
        fold_kernel<<<dim3(1024 * 32), dim3(256), 0, stream>>>(
            ws_ec, x, beta, out, out + OFF_EC);
    } else {
        psa_kernel<false><<<dim3(4 * M_), dim3(256), 0, stream>>>(
            x, beta, out, out + OFF_SC, out + OFF_COV, out + OFF_L, out + OFF_EC,
            nullptr);
    }
}